// Round 1
// 408.455 us; speedup vs baseline: 1.1543x; 1.1543x over previous
//
#include <hip/hip_runtime.h>
#include <hip/hip_fp16.h>

typedef _Float16 half_t;
typedef half_t halfx8 __attribute__((ext_vector_type(8)));
typedef half_t halfx4 __attribute__((ext_vector_type(4)));
typedef float floatx4 __attribute__((ext_vector_type(4)));

#define HID 1024
#define HEADS 16
#define HD 64
#define BATCH 4
#define SEQ 2048
#define MTOT (BATCH * SEQ) /* 8192 */
#define NWELEM (HID * HID) /* 1048576 */

#define MFMA_F16 __builtin_amdgcn_mfma_f32_16x16x32_f16

// Load 8 contiguous elements as halfx8; fp32 source converts on the fly.
__device__ inline halfx8 load8h(const half_t* p) { return *(const halfx8*)p; }
__device__ inline halfx8 load8h(const float* p) {
    floatx4 x = *(const floatx4*)p;
    floatx4 y = *(const floatx4*)(p + 4);
    halfx8 r;
    r[0] = (half_t)x[0]; r[1] = (half_t)x[1];
    r[2] = (half_t)x[2]; r[3] = (half_t)x[3];
    r[4] = (half_t)y[0]; r[5] = (half_t)y[1];
    r[6] = (half_t)y[2]; r[7] = (half_t)y[3];
    return r;
}

// async 16B global->LDS: LDS dest is wave-uniform base + lane*16 (m104/m173);
// global src is per-lane. size arg must be a literal (16).
__device__ __forceinline__ void gl_lds16(const half_t* g, half_t* lds) {
    __builtin_amdgcn_global_load_lds(
        (const __attribute__((address_space(1))) void*)g,
        (__attribute__((address_space(3))) void*)lds, 16, 0, 0);
}

// ---------------------------------------------------------------------------
// Shared GEMM epilogue.  C/D layout: col = lane&15, row = quad*4 + reg
// [m89-verified].
// MODE 0: fp16 -> [B][H][S][D]   (Q, K)
// MODE 1: fp32 -> flat [M, N]    (final)
// MODE 2: fp16 -> [B][H][D][S]   (V transposed; 8B-aligned halfx4 stores)
// ---------------------------------------------------------------------------
template <int MODE, typename TOut>
__device__ __forceinline__ void epilogue_store(
    const floatx4 (&acc)[4][4], const float* __restrict__ bias,
    TOut* __restrict__ Out, int m0, int n0, int wm, int wn, int quad, int l16)
{
    float bvals[4];
#pragma unroll
    for (int nt = 0; nt < 4; ++nt)
        bvals[nt] = bias[n0 + wn + nt * 16 + l16];

#pragma unroll
    for (int mt = 0; mt < 4; ++mt) {
        const int mbase = m0 + wm + mt * 16 + quad * 4;
#pragma unroll
        for (int nt = 0; nt < 4; ++nt) {
            const int n = n0 + wn + nt * 16 + l16;
            if (MODE == 2) {
                const int b = mbase >> 11, s = mbase & (SEQ - 1);
                const int h = n >> 6, d = n & (HD - 1);
                halfx4 st;
#pragma unroll
                for (int r = 0; r < 4; ++r)
                    st[r] = (half_t)(acc[mt][nt][r] + bvals[nt]);
                *(halfx4*)((half_t*)Out +
                    ((((size_t)b * HEADS + h) * HD + d) << 11) + s) = st;
            } else {
#pragma unroll
                for (int r = 0; r < 4; ++r) {
                    const float v = acc[mt][nt][r] + bvals[nt];
                    const int mm  = mbase + r;
                    if (MODE == 0) {
                        const int b = mm >> 11, s = mm & (SEQ - 1);
                        const int h = n >> 6, d = n & (HD - 1);
                        Out[((((size_t)b * HEADS + h) * SEQ + s) << 6) + d] = (TOut)v;
                    } else {
                        Out[(size_t)mm * HID + n] = (TOut)v;
                    }
                }
            }
        }
    }
}

// ---------------------------------------------------------------------------
// Fast GEMM (fp16 A and W): Out = A @ W^T + bias, m97 structure.
// 128x128 tile, BK=32, 256 thr (4 waves 2x2), mfma 16x16x32 f16.
// LDS linear [128][32] fp16 (8 KB each side), staged via global_load_lds
// width=16: each wave stages 2x1KB chunks (16 rows) of A and of B per K-step.
// 2-barrier K-loop (compiler emits vmcnt(0) drain before the 2nd s_barrier).
// ---------------------------------------------------------------------------
template <int MODE, typename TOut>
__global__ __launch_bounds__(256) void gemm16(
    const half_t* __restrict__ A, const half_t* __restrict__ W,
    const float* __restrict__ bias, TOut* __restrict__ Out)
{
    __shared__ half_t As[128 * 32];
    __shared__ half_t Bs[128 * 32];

    const int tid  = threadIdx.x;
    const int m0   = blockIdx.y * 128;
    const int n0   = blockIdx.x * 128;
    const int wave = tid >> 6;
    const int lane = tid & 63;
    const int quad = lane >> 4;
    const int l16  = lane & 15;
    const int wm   = (wave >> 1) * 64;
    const int wn   = (wave & 1) * 64;

    // staging map: chunk c covers LDS bytes [c*1024, +1024) = rows [c*16,+16)
    // (row = 32 halfs = 64 B). Wave w owns chunks 2w, 2w+1 of each matrix.
    // Lane i -> row c*16 + (i>>2), half-col (i&3)*8 (16 B).
    const int c0   = wave * 2;
    const int srow = c0 * 16 + (lane >> 2);
    const int scol = (lane & 3) * 8;
    const half_t* aptr0 = A + (size_t)(m0 + srow) * HID + scol;
    const half_t* aptr1 = aptr0 + (size_t)16 * HID;
    const half_t* bptr0 = W + (size_t)(n0 + srow) * HID + scol;
    const half_t* bptr1 = bptr0 + (size_t)16 * HID;
    half_t* ldsA0 = &As[c0 * 512];
    half_t* ldsA1 = &As[c0 * 512 + 512];
    half_t* ldsB0 = &Bs[c0 * 512];
    half_t* ldsB1 = &Bs[c0 * 512 + 512];

    floatx4 acc[4][4];
    const floatx4 zero4 = {0.f, 0.f, 0.f, 0.f};
#pragma unroll
    for (int mt = 0; mt < 4; ++mt)
#pragma unroll
        for (int nt = 0; nt < 4; ++nt) acc[mt][nt] = zero4;

    for (int k0 = 0; k0 < HID; k0 += 32) {
        __syncthreads();  // prior iter's LDS reads done before overwrite
        gl_lds16(aptr0 + k0, ldsA0);
        gl_lds16(aptr1 + k0, ldsA1);
        gl_lds16(bptr0 + k0, ldsB0);
        gl_lds16(bptr1 + k0, ldsB1);
        __syncthreads();  // staging landed (vmcnt(0) before barrier)

        halfx8 af[4], bfr[4];
#pragma unroll
        for (int t = 0; t < 4; ++t) {
            af[t]  = *(const halfx8*)&As[(wm + t * 16 + l16) * 32 + quad * 8];
            bfr[t] = *(const halfx8*)&Bs[(wn + t * 16 + l16) * 32 + quad * 8];
        }
#pragma unroll
        for (int mt = 0; mt < 4; ++mt)
#pragma unroll
            for (int nt = 0; nt < 4; ++nt)
                acc[mt][nt] = MFMA_F16(af[mt], bfr[nt], acc[mt][nt], 0, 0, 0);
    }

    epilogue_store<MODE, TOut>(acc, bias, Out, m0, n0, wm, wn, quad, l16);
}

// ---------------------------------------------------------------------------
// Legacy GEMM (fp32 A/W, reg-staged cvt) — fallback if ws too small for the
// fp16 pre-convert path.  Unchanged R7-proven structure.
// ---------------------------------------------------------------------------
template <int MODE, typename TA, typename TOut>
__global__ __launch_bounds__(256) void gemm_bt(
    const TA* __restrict__ A, const float* __restrict__ W,
    const float* __restrict__ bias, TOut* __restrict__ Out)
{
    __shared__ half_t As[128][40];
    __shared__ half_t Bs[128][40];

    const int tid  = threadIdx.x;
    const int m0   = blockIdx.y * 128;
    const int n0   = blockIdx.x * 128;
    const int wave = tid >> 6;
    const int lane = tid & 63;
    const int quad = lane >> 4;
    const int l16  = lane & 15;
    const int wm   = (wave >> 1) * 64;
    const int wn   = (wave & 1) * 64;
    const int trow = tid >> 1;
    const int tcol = (tid & 1) * 16;

    const TA*    aptr = A + (size_t)(m0 + trow) * HID + tcol;
    const float* bptr = W + (size_t)(n0 + trow) * HID + tcol;

    floatx4 acc[4][4];
    const floatx4 zero4 = {0.f, 0.f, 0.f, 0.f};
#pragma unroll
    for (int mt = 0; mt < 4; ++mt)
#pragma unroll
        for (int nt = 0; nt < 4; ++nt) acc[mt][nt] = zero4;

    for (int k0 = 0; k0 < HID; k0 += 32) {
        halfx8 av0 = load8h(aptr);
        halfx8 av1 = load8h(aptr + 8);
        halfx8 bv0 = load8h(bptr);
        halfx8 bv1 = load8h(bptr + 8);
        aptr += 32;
        bptr += 32;

        __syncthreads();
        *(halfx8*)&As[trow][tcol]     = av0;
        *(halfx8*)&As[trow][tcol + 8] = av1;
        *(halfx8*)&Bs[trow][tcol]     = bv0;
        *(halfx8*)&Bs[trow][tcol + 8] = bv1;
        __syncthreads();

        halfx8 af[4], bfr[4];
#pragma unroll
        for (int t = 0; t < 4; ++t) {
            af[t]  = *(const halfx8*)&As[wm + t * 16 + l16][quad * 8];
            bfr[t] = *(const halfx8*)&Bs[wn + t * 16 + l16][quad * 8];
        }
#pragma unroll
        for (int mt = 0; mt < 4; ++mt)
#pragma unroll
            for (int nt = 0; nt < 4; ++nt)
                acc[mt][nt] = MFMA_F16(af[mt], bfr[nt], acc[mt][nt], 0, 0, 0);
    }

    epilogue_store<MODE, TOut>(acc, bias, Out, m0, n0, wm, wn, quad, l16);
}

// ---------------------------------------------------------------------------
// fp32 -> fp16 conversion kernels (memory-bound, vectorized 8/thread).
// ---------------------------------------------------------------------------
__global__ __launch_bounds__(256) void cvt_act(
    const float* __restrict__ in, half_t* __restrict__ out)
{
    const size_t i = ((size_t)blockIdx.x * 256 + threadIdx.x) * 8;
    *(halfx8*)(out + i) = load8h(in + i);
}

__global__ __launch_bounds__(256) void cvt_w4(
    const float* __restrict__ w0, const float* __restrict__ w1,
    const float* __restrict__ w2, const float* __restrict__ w3,
    half_t* __restrict__ out)
{
    const int t = blockIdx.y;
    const float* src = (t == 0) ? w0 : (t == 1) ? w1 : (t == 2) ? w2 : w3;
    const size_t i = ((size_t)blockIdx.x * 256 + threadIdx.x) * 8;
    *(halfx8*)(out + (size_t)t * NWELEM + i) = load8h(src + i);
}

// ---------------------------------------------------------------------------
// Causal flash attention, fp16 (unscaled logits per reference). UNCHANGED.
// grid: (B*H, S/128). Block 256 thr / 4 waves; wave w owns q-rows
// [q0+w*32, +32) (2 m-tiles). k-tiles of 64; ktiles = 2*qt+2; fully-masked
// tiles predicated off (barriers stay uniform). V arrives pre-transposed
// [b][h][d][s].
// ---------------------------------------------------------------------------
__global__ __launch_bounds__(256) void attn_kernel(
    const half_t* __restrict__ Q, const half_t* __restrict__ K,
    const half_t* __restrict__ VT, half_t* __restrict__ O)
{
    __shared__ half_t Ks[64][72];      // [k][d]
    __shared__ half_t Vt[64][72];      // [d][k]
    __shared__ half_t Pw[4][32][72];   // per-wave P round-trip

    const int bh  = blockIdx.x;                      // b*HEADS + h
    const int qt  = (gridDim.y - 1) - blockIdx.y;    // heaviest tiles first
    const int q0  = qt * 128;
    const int tid = threadIdx.x;
    const int wave = tid >> 6;
    const int lane = tid & 63;
    const int quad = lane >> 4;
    const int l16  = lane & 15;

    const half_t* Qb  = Q  + (size_t)bh * SEQ * HD;
    const half_t* Kb  = K  + (size_t)bh * SEQ * HD;
    const half_t* VTb = VT + (size_t)bh * HD * SEQ;

    halfx8 aq[2][2];
#pragma unroll
    for (int mt = 0; mt < 2; ++mt) {
        const half_t* p = Qb + (size_t)(q0 + wave * 32 + mt * 16 + l16) * HD + quad * 8;
        aq[mt][0] = *(const halfx8*)p;
        aq[mt][1] = *(const halfx8*)(p + 32);
    }

    const floatx4 zero4 = {0.f, 0.f, 0.f, 0.f};
    floatx4 oacc[2][4];
    float mrow[2][4], lrow[2][4];
#pragma unroll
    for (int mt = 0; mt < 2; ++mt)
#pragma unroll
        for (int i = 0; i < 4; ++i) {
            oacc[mt][i] = zero4;
            mrow[mt][i] = -3.0e38f;
            lrow[mt][i] = 0.f;
        }

    const int srow = tid >> 2;
    const int scol = (tid & 3) * 16;
    const int ktiles = 2 * qt + 2;

    for (int kt = 0; kt < ktiles; ++kt) {
        const int k0 = kt * 64;
        __syncthreads();
        {
            const half_t* ksrc = Kb + (size_t)(k0 + srow) * HD + scol;
            *(halfx8*)&Ks[srow][scol]     = *(const halfx8*)ksrc;
            *(halfx8*)&Ks[srow][scol + 8] = *(const halfx8*)(ksrc + 8);
            const half_t* vsrc = VTb + (size_t)srow * SEQ + k0 + scol;
            *(halfx8*)&Vt[srow][scol]     = *(const halfx8*)vsrc;
            *(halfx8*)&Vt[srow][scol + 8] = *(const halfx8*)(vsrc + 8);
        }
        __syncthreads();

        const bool active = (k0 <= q0 + wave * 32 + 31);

        if (active) {
            floatx4 sacc[2][4];
#pragma unroll
            for (int mt = 0; mt < 2; ++mt)
#pragma unroll
                for (int nt = 0; nt < 4; ++nt) sacc[mt][nt] = zero4;
#pragma unroll
            for (int nt = 0; nt < 4; ++nt) {
                halfx8 bk0 = *(const halfx8*)&Ks[nt * 16 + l16][quad * 8];
                halfx8 bk1 = *(const halfx8*)&Ks[nt * 16 + l16][quad * 8 + 32];
#pragma unroll
                for (int mt = 0; mt < 2; ++mt) {
                    sacc[mt][nt] = MFMA_F16(aq[mt][0], bk0, sacc[mt][nt], 0, 0, 0);
                    sacc[mt][nt] = MFMA_F16(aq[mt][1], bk1, sacc[mt][nt], 0, 0, 0);
                }
            }

            if (kt >= 2 * qt) {
#pragma unroll
                for (int mt = 0; mt < 2; ++mt)
#pragma unroll
                    for (int nt = 0; nt < 4; ++nt) {
                        const int kg = k0 + nt * 16 + l16;
#pragma unroll
                        for (int r = 0; r < 4; ++r) {
                            const int qg = q0 + wave * 32 + mt * 16 + quad * 4 + r;
                            if (kg > qg) sacc[mt][nt][r] = -1.0e30f;
                        }
                    }
            }

#pragma unroll
            for (int mt = 0; mt < 2; ++mt) {
                float alpha[4];
#pragma unroll
                for (int r = 0; r < 4; ++r) {
                    float mx = fmaxf(fmaxf(sacc[mt][0][r], sacc[mt][1][r]),
                                     fmaxf(sacc[mt][2][r], sacc[mt][3][r]));
                    mx = fmaxf(mx, __shfl_xor(mx, 1));
                    mx = fmaxf(mx, __shfl_xor(mx, 2));
                    mx = fmaxf(mx, __shfl_xor(mx, 4));
                    mx = fmaxf(mx, __shfl_xor(mx, 8));
                    const float mnew = fmaxf(mrow[mt][r], mx);
                    alpha[r]    = __expf(mrow[mt][r] - mnew);
                    mrow[mt][r] = mnew;
                }
                float rsum[4] = {0.f, 0.f, 0.f, 0.f};
#pragma unroll
                for (int nt = 0; nt < 4; ++nt)
#pragma unroll
                    for (int r = 0; r < 4; ++r) {
                        const float p = __expf(sacc[mt][nt][r] - mrow[mt][r]);
                        sacc[mt][nt][r] = p;
                        rsum[r] += p;
                    }
#pragma unroll
                for (int r = 0; r < 4; ++r) {
                    float s = rsum[r];
                    s += __shfl_xor(s, 1);
                    s += __shfl_xor(s, 2);
                    s += __shfl_xor(s, 4);
                    s += __shfl_xor(s, 8);
                    lrow[mt][r] = lrow[mt][r] * alpha[r] + s;
                }
#pragma unroll
                for (int dt = 0; dt < 4; ++dt)
#pragma unroll
                    for (int r = 0; r < 4; ++r) oacc[mt][dt][r] *= alpha[r];

#pragma unroll
                for (int nt = 0; nt < 4; ++nt)
#pragma unroll
                    for (int r = 0; r < 4; ++r)
                        Pw[wave][mt * 16 + quad * 4 + r][nt * 16 + l16] =
                            (half_t)sacc[mt][nt][r];
            }
        }

        __syncthreads();

        if (active) {
#pragma unroll
            for (int s2 = 0; s2 < 2; ++s2) {
                halfx8 ap0 = *(const halfx8*)&Pw[wave][l16][s2 * 32 + quad * 8];
                halfx8 ap1 = *(const halfx8*)&Pw[wave][16 + l16][s2 * 32 + quad * 8];
#pragma unroll
                for (int dt = 0; dt < 4; ++dt) {
                    halfx8 bv = *(const halfx8*)&Vt[dt * 16 + l16][s2 * 32 + quad * 8];
                    oacc[0][dt] = MFMA_F16(ap0, bv, oacc[0][dt], 0, 0, 0);
                    oacc[1][dt] = MFMA_F16(ap1, bv, oacc[1][dt], 0, 0, 0);
                }
            }
        }
    }

    const int b = bh >> 4, h = bh & (HEADS - 1);
#pragma unroll
    for (int mt = 0; mt < 2; ++mt)
#pragma unroll
        for (int dt = 0; dt < 4; ++dt)
#pragma unroll
            for (int r = 0; r < 4; ++r) {
                const int q = q0 + wave * 32 + mt * 16 + quad * 4 + r;
                const int d = h * HD + dt * 16 + l16;
                O[(size_t)(b * SEQ + q) * HID + d] =
                    (half_t)(oacc[mt][dt][r] / lrow[mt][r]);
            }
}

// ---------------------------------------------------------------------------
extern "C" void kernel_launch(void* const* d_in, const int* in_sizes, int n_in,
                              void* d_out, int out_size, void* d_ws, size_t ws_size,
                              hipStream_t stream)
{
    const float* query = (const float*)d_in[0];
    const float* key   = (const float*)d_in[1];
    const float* value = (const float*)d_in[2];
    const float* Wq    = (const float*)d_in[3];
    const float* bq    = (const float*)d_in[4];
    const float* Wk    = (const float*)d_in[5];
    const float* bk    = (const float*)d_in[6];
    const float* Wv    = (const float*)d_in[7];
    const float* bv    = (const float*)d_in[8];
    const float* Wo    = (const float*)d_in[9];
    const float* bo    = (const float*)d_in[10];
    float* out = (float*)d_out;

    // workspace (fp16): Qp, Kp [B][H][S][D]; VpT [B][H][D][S]; Ob [M][HID];
    // W16 [4][HID][HID].  Fast path needs 75.5 MB; the 67.1 MB base layout is
    // the proven bound, so guard and fall back to the fp32-staged GEMM if the
    // extra 8.4 MB for W16 isn't there.  The single fp16-activation staging
    // buffer aliases the Ob slot (dead until attn runs): conv->GEMM pairs are
    // serialized per activation (q, then k, then v).
    const size_t NE = (size_t)MTOT * HID;
    half_t* Qp  = (half_t*)d_ws;
    half_t* Kp  = Qp  + NE;
    half_t* VpT = Kp  + NE;
    half_t* Ob  = VpT + NE;
    half_t* W16 = Ob  + NE;
    const size_t need = (4 * NE + 4 * (size_t)NWELEM) * sizeof(half_t);

    dim3 gg(HID / 128, MTOT / 128);     // (8, 64)
    dim3 ga(BATCH * HEADS, SEQ / 128);  // (64, 16)

    if (ws_size >= need) {
        half_t* act16 = Ob;  // Ob slot reused as staging pre-attn
        const unsigned actBlocks = (unsigned)(NE / 2048);      // 4096
        const unsigned wBlocks   = (unsigned)(NWELEM / 2048);  // 512

        cvt_w4<<<dim3(wBlocks, 4), 256, 0, stream>>>(Wq, Wk, Wv, Wo, W16);

        cvt_act<<<actBlocks, 256, 0, stream>>>(query, act16);
        gemm16<0, half_t><<<gg, 256, 0, stream>>>(act16, W16, bq, Qp);
        cvt_act<<<actBlocks, 256, 0, stream>>>(key, act16);
        gemm16<0, half_t><<<gg, 256, 0, stream>>>(act16, W16 + NWELEM, bk, Kp);
        cvt_act<<<actBlocks, 256, 0, stream>>>(value, act16);
        gemm16<2, half_t><<<gg, 256, 0, stream>>>(act16, W16 + 2 * (size_t)NWELEM, bv, VpT);

        attn_kernel<<<ga, 256, 0, stream>>>(Qp, Kp, VpT, Ob);

        gemm16<1, float><<<gg, 256, 0, stream>>>(Ob, W16 + 3 * (size_t)NWELEM, bo, out);
    } else {
        // legacy R7 path (proven at 471 us)
        gemm_bt<0, float, half_t><<<gg, 256, 0, stream>>>(query, Wq, bq, Qp);
        gemm_bt<0, float, half_t><<<gg, 256, 0, stream>>>(key,   Wk, bk, Kp);
        gemm_bt<2, float, half_t><<<gg, 256, 0, stream>>>(value, Wv, bv, VpT);
        attn_kernel<<<ga, 256, 0, stream>>>(Qp, Kp, VpT, Ob);
        gemm_bt<1, half_t, float><<<gg, 256, 0, stream>>>(Ob, Wo, bo, out);
    }
}

// Round 2
// 362.141 us; speedup vs baseline: 1.3019x; 1.1279x over previous
//
#include <hip/hip_runtime.h>
#include <hip/hip_fp16.h>

typedef _Float16 half_t;
typedef half_t halfx8 __attribute__((ext_vector_type(8)));
typedef half_t halfx4 __attribute__((ext_vector_type(4)));
typedef float floatx4 __attribute__((ext_vector_type(4)));

#define HID 1024
#define HEADS 16
#define HD 64
#define BATCH 4
#define SEQ 2048
#define MTOT (BATCH * SEQ) /* 8192 */
#define NWELEM (HID * HID) /* 1048576 */

#define MFMA_F16 __builtin_amdgcn_mfma_f32_16x16x32_f16

// Load 8 contiguous elements as halfx8; fp32 source converts on the fly.
__device__ inline halfx8 load8h(const half_t* p) { return *(const halfx8*)p; }
__device__ inline halfx8 load8h(const float* p) {
    floatx4 x = *(const floatx4*)p;
    floatx4 y = *(const floatx4*)(p + 4);
    halfx8 r;
    r[0] = (half_t)x[0]; r[1] = (half_t)x[1];
    r[2] = (half_t)x[2]; r[3] = (half_t)x[3];
    r[4] = (half_t)y[0]; r[5] = (half_t)y[1];
    r[6] = (half_t)y[2]; r[7] = (half_t)y[3];
    return r;
}

// pack two fp32 -> one dword of 2 fp16 (RTN, matches (half_t) cast numerics)
__device__ __forceinline__ uint32_t pack2h(float a, float b) {
    union { half_t h[2]; uint32_t u; } r;
    r.h[0] = (half_t)a; r.h[1] = (half_t)b;
    return r.u;
}

// async 16B global->LDS: LDS dest is wave-uniform base + lane*16 (m104/m173);
// global src is per-lane. size arg must be a literal (16).
__device__ __forceinline__ void gl_lds16(const half_t* g, half_t* lds) {
    __builtin_amdgcn_global_load_lds(
        (const __attribute__((address_space(1))) void*)g,
        (__attribute__((address_space(3))) void*)lds, 16, 0, 0);
}

// ---------------------------------------------------------------------------
// Shared GEMM epilogue.  C/D layout: col = lane&15, row = quad*4 + reg
// [m89-verified].
// MODE 0: fp16 -> [B][H][S][D]   (Q, K)
// MODE 1: fp32 -> flat [M, N]    (final)
// MODE 2: fp16 -> [B][H][D][S]   (V transposed; 8B-aligned halfx4 stores)
// ---------------------------------------------------------------------------
template <int MODE, typename TOut>
__device__ __forceinline__ void epilogue_store(
    const floatx4 (&acc)[4][4], const float* __restrict__ bias,
    TOut* __restrict__ Out, int m0, int n0, int wm, int wn, int quad, int l16)
{
    float bvals[4];
#pragma unroll
    for (int nt = 0; nt < 4; ++nt)
        bvals[nt] = bias[n0 + wn + nt * 16 + l16];

#pragma unroll
    for (int mt = 0; mt < 4; ++mt) {
        const int mbase = m0 + wm + mt * 16 + quad * 4;
#pragma unroll
        for (int nt = 0; nt < 4; ++nt) {
            const int n = n0 + wn + nt * 16 + l16;
            if (MODE == 2) {
                const int b = mbase >> 11, s = mbase & (SEQ - 1);
                const int h = n >> 6, d = n & (HD - 1);
                halfx4 st;
#pragma unroll
                for (int r = 0; r < 4; ++r)
                    st[r] = (half_t)(acc[mt][nt][r] + bvals[nt]);
                *(halfx4*)((half_t*)Out +
                    ((((size_t)b * HEADS + h) * HD + d) << 11) + s) = st;
            } else {
#pragma unroll
                for (int r = 0; r < 4; ++r) {
                    const float v = acc[mt][nt][r] + bvals[nt];
                    const int mm  = mbase + r;
                    if (MODE == 0) {
                        const int b = mm >> 11, s = mm & (SEQ - 1);
                        const int h = n >> 6, d = n & (HD - 1);
                        Out[((((size_t)b * HEADS + h) * SEQ + s) << 6) + d] = (TOut)v;
                    } else {
                        Out[(size_t)mm * HID + n] = (TOut)v;
                    }
                }
            }
        }
    }
}

// ---------------------------------------------------------------------------
// Fast GEMM (fp16 A and W): Out = A @ W^T + bias, m97 structure.
// 128x128 tile, BK=32, 256 thr (4 waves 2x2), mfma 16x16x32 f16.
// LDS linear [128][32] fp16, staged via global_load_lds width=16.
// XCD-aware swizzle: nwg=512 (%8==0); each XCD owns 8 contiguous m-rows
// x all n -> per-XCD L2 footprint = A-panel 2MB + W 2MB = 4MB (one L2).
// ---------------------------------------------------------------------------
template <int MODE, typename TOut>
__global__ __launch_bounds__(256) void gemm16(
    const half_t* __restrict__ A, const half_t* __restrict__ W,
    const float* __restrict__ bias, TOut* __restrict__ Out)
{
    __shared__ half_t As[128 * 32];
    __shared__ half_t Bs[128 * 32];

    const int tid  = threadIdx.x;
    // XCD swizzle (T1): id%8 = XCD under round-robin dispatch; give each XCD
    // a contiguous chunk of tile-space.
    const int id   = blockIdx.y * gridDim.x + blockIdx.x;
    const int cpx  = (gridDim.x * gridDim.y) >> 3;
    const int swz  = (id & 7) * cpx + (id >> 3);
    const int m0   = (swz >> 3) * 128;          // gridDim.x == 8
    const int n0   = (swz & 7) * 128;
    const int wave = tid >> 6;
    const int lane = tid & 63;
    const int quad = lane >> 4;
    const int l16  = lane & 15;
    const int wm   = (wave >> 1) * 64;
    const int wn   = (wave & 1) * 64;

    // staging map: chunk c covers LDS bytes [c*1024, +1024) = rows [c*16,+16)
    // (row = 32 halfs = 64 B). Wave w owns chunks 2w, 2w+1 of each matrix.
    const int c0   = wave * 2;
    const int srow = c0 * 16 + (lane >> 2);
    const int scol = (lane & 3) * 8;
    const half_t* aptr0 = A + (size_t)(m0 + srow) * HID + scol;
    const half_t* aptr1 = aptr0 + (size_t)16 * HID;
    const half_t* bptr0 = W + (size_t)(n0 + srow) * HID + scol;
    const half_t* bptr1 = bptr0 + (size_t)16 * HID;
    half_t* ldsA0 = &As[c0 * 512];
    half_t* ldsA1 = &As[c0 * 512 + 512];
    half_t* ldsB0 = &Bs[c0 * 512];
    half_t* ldsB1 = &Bs[c0 * 512 + 512];

    floatx4 acc[4][4];
    const floatx4 zero4 = {0.f, 0.f, 0.f, 0.f};
#pragma unroll
    for (int mt = 0; mt < 4; ++mt)
#pragma unroll
        for (int nt = 0; nt < 4; ++nt) acc[mt][nt] = zero4;

    for (int k0 = 0; k0 < HID; k0 += 32) {
        __syncthreads();  // prior iter's LDS reads done before overwrite
        gl_lds16(aptr0 + k0, ldsA0);
        gl_lds16(aptr1 + k0, ldsA1);
        gl_lds16(bptr0 + k0, ldsB0);
        gl_lds16(bptr1 + k0, ldsB1);
        __syncthreads();  // staging landed (vmcnt(0) before barrier)

        halfx8 af[4], bfr[4];
#pragma unroll
        for (int t = 0; t < 4; ++t) {
            af[t]  = *(const halfx8*)&As[(wm + t * 16 + l16) * 32 + quad * 8];
            bfr[t] = *(const halfx8*)&Bs[(wn + t * 16 + l16) * 32 + quad * 8];
        }
#pragma unroll
        for (int mt = 0; mt < 4; ++mt)
#pragma unroll
            for (int nt = 0; nt < 4; ++nt)
                acc[mt][nt] = MFMA_F16(af[mt], bfr[nt], acc[mt][nt], 0, 0, 0);
    }

    epilogue_store<MODE, TOut>(acc, bias, Out, m0, n0, wm, wn, quad, l16);
}

// ---------------------------------------------------------------------------
// Legacy GEMM (fp32 A/W, reg-staged cvt) — fallback if ws too small for the
// fp16 pre-convert path.
// ---------------------------------------------------------------------------
template <int MODE, typename TA, typename TOut>
__global__ __launch_bounds__(256) void gemm_bt(
    const TA* __restrict__ A, const float* __restrict__ W,
    const float* __restrict__ bias, TOut* __restrict__ Out)
{
    __shared__ half_t As[128][40];
    __shared__ half_t Bs[128][40];

    const int tid  = threadIdx.x;
    const int m0   = blockIdx.y * 128;
    const int n0   = blockIdx.x * 128;
    const int wave = tid >> 6;
    const int lane = tid & 63;
    const int quad = lane >> 4;
    const int l16  = lane & 15;
    const int wm   = (wave >> 1) * 64;
    const int wn   = (wave & 1) * 64;
    const int trow = tid >> 1;
    const int tcol = (tid & 1) * 16;

    const TA*    aptr = A + (size_t)(m0 + trow) * HID + tcol;
    const float* bptr = W + (size_t)(n0 + trow) * HID + tcol;

    floatx4 acc[4][4];
    const floatx4 zero4 = {0.f, 0.f, 0.f, 0.f};
#pragma unroll
    for (int mt = 0; mt < 4; ++mt)
#pragma unroll
        for (int nt = 0; nt < 4; ++nt) acc[mt][nt] = zero4;

    for (int k0 = 0; k0 < HID; k0 += 32) {
        halfx8 av0 = load8h(aptr);
        halfx8 av1 = load8h(aptr + 8);
        halfx8 bv0 = load8h(bptr);
        halfx8 bv1 = load8h(bptr + 8);
        aptr += 32;
        bptr += 32;

        __syncthreads();
        *(halfx8*)&As[trow][tcol]     = av0;
        *(halfx8*)&As[trow][tcol + 8] = av1;
        *(halfx8*)&Bs[trow][tcol]     = bv0;
        *(halfx8*)&Bs[trow][tcol + 8] = bv1;
        __syncthreads();

        halfx8 af[4], bfr[4];
#pragma unroll
        for (int t = 0; t < 4; ++t) {
            af[t]  = *(const halfx8*)&As[wm + t * 16 + l16][quad * 8];
            bfr[t] = *(const halfx8*)&Bs[wn + t * 16 + l16][quad * 8];
        }
#pragma unroll
        for (int mt = 0; mt < 4; ++mt)
#pragma unroll
            for (int nt = 0; nt < 4; ++nt)
                acc[mt][nt] = MFMA_F16(af[mt], bfr[nt], acc[mt][nt], 0, 0, 0);
    }

    epilogue_store<MODE, TOut>(acc, bias, Out, m0, n0, wm, wn, quad, l16);
}

// ---------------------------------------------------------------------------
// fp32 -> fp16 conversion kernels (memory-bound, vectorized 8/thread).
// ---------------------------------------------------------------------------
__global__ __launch_bounds__(256) void cvt_act(
    const float* __restrict__ in, half_t* __restrict__ out)
{
    const size_t i = ((size_t)blockIdx.x * 256 + threadIdx.x) * 8;
    *(halfx8*)(out + i) = load8h(in + i);
}

__global__ __launch_bounds__(256) void cvt_w4(
    const float* __restrict__ w0, const float* __restrict__ w1,
    const float* __restrict__ w2, const float* __restrict__ w3,
    half_t* __restrict__ out)
{
    const int t = blockIdx.y;
    const float* src = (t == 0) ? w0 : (t == 1) ? w1 : (t == 2) ? w2 : w3;
    const size_t i = ((size_t)blockIdx.x * 256 + threadIdx.x) * 8;
    *(halfx8*)(out + (size_t)t * NWELEM + i) = load8h(src + i);
}

// ---------------------------------------------------------------------------
// Causal flash attention, fp16, SWAPPED-QK^T structure (in-register softmax).
// grid: (B*H, S/128). Block 256 thr / 4 waves; wave w owns q-rows
// [q0+w*32, +32). k-tiles of 64; ktiles = 2*qt+2; fully-masked tiles
// predicated off (barriers stay uniform). V arrives pre-transposed [b][h][d][s].
//
// QK^T computed as MFMA(K_frag, Q_frag) -> S^T fragments: lane (quad,l16)
// holds S[kv = k0+nt*16+quad*4+r][q = q0+w*32+mt*16+l16].  All 16 of a
// lane's values share one q -> softmax row-reduce = lane-local + shfl_xor
// 16/32 (cross-quad).  P stays in registers: pack to fp16 dwords, then a
// 32-shfl+select redistribution produces the PV B-fragment [n=q][k=kv].
// PV = MFMA(V^T_frag, P_frag) -> O^T fragments; epilogue halfx4 stores
// (4 consecutive d per register).  No P LDS buffer, 2 barriers/tile.
// ---------------------------------------------------------------------------
__global__ __launch_bounds__(256) void attn_kernel(
    const half_t* __restrict__ Q, const half_t* __restrict__ K,
    const half_t* __restrict__ VT, half_t* __restrict__ O)
{
    __shared__ half_t Ks[64][72];      // [k][d]
    __shared__ half_t Vt[64][72];      // [d][k]

    const int bh  = blockIdx.x;                      // b*HEADS + h
    const int qt  = (gridDim.y - 1) - blockIdx.y;    // heaviest tiles first
    const int q0  = qt * 128;
    const int tid = threadIdx.x;
    const int wave = tid >> 6;
    const int lane = tid & 63;
    const int quad = lane >> 4;
    const int l16  = lane & 15;

    const half_t* Qb  = Q  + (size_t)bh * SEQ * HD;
    const half_t* Kb  = K  + (size_t)bh * SEQ * HD;
    const half_t* VTb = VT + (size_t)bh * HD * SEQ;

    // Q fragments (B-operand of swapped QK^T): B[n=q=l16][k=d=quad*8+j]
    halfx8 aq[2][2];
#pragma unroll
    for (int mt = 0; mt < 2; ++mt) {
        const half_t* p = Qb + (size_t)(q0 + wave * 32 + mt * 16 + l16) * HD + quad * 8;
        aq[mt][0] = *(const halfx8*)p;
        aq[mt][1] = *(const halfx8*)(p + 32);
    }

    const floatx4 zero4 = {0.f, 0.f, 0.f, 0.f};
    floatx4 oaccT[2][4];   // [mt][dt]: lane holds O[q=mt*16+l16][d=dt*16+quad*4+r]
    float mrow[2], lrow[2];
#pragma unroll
    for (int mt = 0; mt < 2; ++mt) {
        mrow[mt] = -3.0e38f;
        lrow[mt] = 0.f;
#pragma unroll
        for (int dt = 0; dt < 4; ++dt) oaccT[mt][dt] = zero4;
    }

    const int srow = tid >> 2;         // 0..63
    const int scol = (tid & 3) * 16;   // 0,16,32,48
    const int ktiles = 2 * qt + 2;

    union U8 { halfx8 h; uint32_t u[4]; };

    for (int kt = 0; kt < ktiles; ++kt) {
        const int k0 = kt * 64;
        __syncthreads();  // prior iter's Ks/Vt reads done
        {
            const half_t* ksrc = Kb + (size_t)(k0 + srow) * HD + scol;
            *(halfx8*)&Ks[srow][scol]     = *(const halfx8*)ksrc;
            *(halfx8*)&Ks[srow][scol + 8] = *(const halfx8*)(ksrc + 8);
            const half_t* vsrc = VTb + (size_t)srow * SEQ + k0 + scol;
            *(halfx8*)&Vt[srow][scol]     = *(const halfx8*)vsrc;
            *(halfx8*)&Vt[srow][scol + 8] = *(const halfx8*)(vsrc + 8);
        }
        __syncthreads();

        // wave-uniform activity predicate (no continue: barriers stay uniform)
        const bool active = (k0 <= q0 + wave * 32 + 31);

        if (active) {
            // S^T: sacc[mt][nt] rows kv, cols q (swapped operands)
            floatx4 sacc[2][4];
#pragma unroll
            for (int mt = 0; mt < 2; ++mt)
#pragma unroll
                for (int nt = 0; nt < 4; ++nt) sacc[mt][nt] = zero4;
#pragma unroll
            for (int nt = 0; nt < 4; ++nt) {
                halfx8 bk0 = *(const halfx8*)&Ks[nt * 16 + l16][quad * 8];
                halfx8 bk1 = *(const halfx8*)&Ks[nt * 16 + l16][quad * 8 + 32];
#pragma unroll
                for (int mt = 0; mt < 2; ++mt) {
                    sacc[mt][nt] = MFMA_F16(bk0, aq[mt][0], sacc[mt][nt], 0, 0, 0);
                    sacc[mt][nt] = MFMA_F16(bk1, aq[mt][1], sacc[mt][nt], 0, 0, 0);
                }
            }

            if (kt >= 2 * qt) {  // diagonal region: mask kv > q
#pragma unroll
                for (int mt = 0; mt < 2; ++mt) {
                    const int qg = q0 + wave * 32 + mt * 16 + l16;
#pragma unroll
                    for (int nt = 0; nt < 4; ++nt) {
                        const int kg = k0 + nt * 16 + quad * 4;
#pragma unroll
                        for (int r = 0; r < 4; ++r)
                            if (kg + r > qg) sacc[mt][nt][r] = -1.0e30f;
                    }
                }
            }

            // in-register online softmax (per lane = per q row, 16 vals)
            uint32_t pk[2][4][2];
#pragma unroll
            for (int mt = 0; mt < 2; ++mt) {
                float mx = sacc[mt][0][0];
#pragma unroll
                for (int nt = 0; nt < 4; ++nt)
#pragma unroll
                    for (int r = 0; r < 4; ++r)
                        if (nt | r) mx = fmaxf(mx, sacc[mt][nt][r]);
                mx = fmaxf(mx, __shfl_xor(mx, 16));
                mx = fmaxf(mx, __shfl_xor(mx, 32));
                const float mnew  = fmaxf(mrow[mt], mx);
                const float alpha = __expf(mrow[mt] - mnew);
                mrow[mt] = mnew;

                float rsum = 0.f;
#pragma unroll
                for (int nt = 0; nt < 4; ++nt)
#pragma unroll
                    for (int r = 0; r < 4; ++r) {
                        const float p = __expf(sacc[mt][nt][r] - mnew);
                        sacc[mt][nt][r] = p;
                        rsum += p;
                    }
#pragma unroll
                for (int nt = 0; nt < 4; ++nt) {
                    pk[mt][nt][0] = pack2h(sacc[mt][nt][0], sacc[mt][nt][1]);
                    pk[mt][nt][1] = pack2h(sacc[mt][nt][2], sacc[mt][nt][3]);
                }
                rsum += __shfl_xor(rsum, 16);
                rsum += __shfl_xor(rsum, 32);
                lrow[mt] = lrow[mt] * alpha + rsum;
#pragma unroll
                for (int dt = 0; dt < 4; ++dt) oaccT[mt][dt] *= alpha;
            }

            // redistribute P^T C-layout -> PV B-frag [n=q=l16][k=kv=quad*8+j].
            // Target word w of s2 pulls from lane l16+16*(2*(quad&1)+(w>>1)),
            // register nt=2*s2+(quad>>1), h=w&1.  nt depends on TARGET quad ->
            // pull both nt candidates and select.
            U8 pb[2][2];  // [mt][s2]
#pragma unroll
            for (int mt = 0; mt < 2; ++mt)
#pragma unroll
                for (int s2 = 0; s2 < 2; ++s2)
#pragma unroll
                    for (int w = 0; w < 4; ++w) {
                        const int src = l16 + ((quad & 1) << 5) + ((w >> 1) << 4);
                        const uint32_t lo =
                            (uint32_t)__shfl((int)pk[mt][2 * s2][w & 1], src, 64);
                        const uint32_t hi =
                            (uint32_t)__shfl((int)pk[mt][2 * s2 + 1][w & 1], src, 64);
                        pb[mt][s2].u[w] = (quad >> 1) ? hi : lo;
                    }

            // PV: O^T = MFMA(A=V^T frag, B=P frag)
#pragma unroll
            for (int s2 = 0; s2 < 2; ++s2)
#pragma unroll
                for (int dt = 0; dt < 4; ++dt) {
                    halfx8 bv = *(const halfx8*)&Vt[dt * 16 + l16][s2 * 32 + quad * 8];
                    oaccT[0][dt] = MFMA_F16(bv, pb[0][s2].h, oaccT[0][dt], 0, 0, 0);
                    oaccT[1][dt] = MFMA_F16(bv, pb[1][s2].h, oaccT[1][dt], 0, 0, 0);
                }
        }
    }

    // epilogue: O^T fragment -> Ob[b][q][h*64+d], halfx4 along d
    const int b = bh >> 4, h = bh & (HEADS - 1);
#pragma unroll
    for (int mt = 0; mt < 2; ++mt) {
        const int q = q0 + wave * 32 + mt * 16 + l16;
#pragma unroll
        for (int dt = 0; dt < 4; ++dt) {
            halfx4 st;
#pragma unroll
            for (int r = 0; r < 4; ++r)
                st[r] = (half_t)(oaccT[mt][dt][r] / lrow[mt]);
            *(halfx4*)(O + (size_t)(b * SEQ + q) * HID +
                       h * HD + dt * 16 + quad * 4) = st;
        }
    }
}

// ---------------------------------------------------------------------------
extern "C" void kernel_launch(void* const* d_in, const int* in_sizes, int n_in,
                              void* d_out, int out_size, void* d_ws, size_t ws_size,
                              hipStream_t stream)
{
    const float* query = (const float*)d_in[0];
    const float* key   = (const float*)d_in[1];
    const float* value = (const float*)d_in[2];
    const float* Wq    = (const float*)d_in[3];
    const float* bq    = (const float*)d_in[4];
    const float* Wk    = (const float*)d_in[5];
    const float* bk    = (const float*)d_in[6];
    const float* Wv    = (const float*)d_in[7];
    const float* bv    = (const float*)d_in[8];
    const float* Wo    = (const float*)d_in[9];
    const float* bo    = (const float*)d_in[10];
    float* out = (float*)d_out;

    // workspace (fp16): Qp, Kp [B][H][S][D]; VpT [B][H][D][S]; Ob [M][HID];
    // W16 [4][HID][HID].  Fast path needs 75.5 MB (proven R1); fall back to
    // the fp32-staged GEMM if the extra 8.4 MB for W16 isn't there.  The
    // single fp16-activation staging buffer aliases the Ob slot (dead until
    // attn runs): conv->GEMM pairs are serialized per activation.
    const size_t NE = (size_t)MTOT * HID;
    half_t* Qp  = (half_t*)d_ws;
    half_t* Kp  = Qp  + NE;
    half_t* VpT = Kp  + NE;
    half_t* Ob  = VpT + NE;
    half_t* W16 = Ob  + NE;
    const size_t need = (4 * NE + 4 * (size_t)NWELEM) * sizeof(half_t);

    dim3 gg(HID / 128, MTOT / 128);     // (8, 64)
    dim3 ga(BATCH * HEADS, SEQ / 128);  // (64, 16)

    if (ws_size >= need) {
        half_t* act16 = Ob;  // Ob slot reused as staging pre-attn
        const unsigned actBlocks = (unsigned)(NE / 2048);      // 4096
        const unsigned wBlocks   = (unsigned)(NWELEM / 2048);  // 512

        cvt_w4<<<dim3(wBlocks, 4), 256, 0, stream>>>(Wq, Wk, Wv, Wo, W16);

        cvt_act<<<actBlocks, 256, 0, stream>>>(query, act16);
        gemm16<0, half_t><<<gg, 256, 0, stream>>>(act16, W16, bq, Qp);
        cvt_act<<<actBlocks, 256, 0, stream>>>(key, act16);
        gemm16<0, half_t><<<gg, 256, 0, stream>>>(act16, W16 + NWELEM, bk, Kp);
        cvt_act<<<actBlocks, 256, 0, stream>>>(value, act16);
        gemm16<2, half_t><<<gg, 256, 0, stream>>>(act16, W16 + 2 * (size_t)NWELEM, bv, VpT);

        attn_kernel<<<ga, 256, 0, stream>>>(Qp, Kp, VpT, Ob);

        gemm16<1, float><<<gg, 256, 0, stream>>>(Ob, W16 + 3 * (size_t)NWELEM, bo, out);
    } else {
        // legacy fallback path
        gemm_bt<0, float, half_t><<<gg, 256, 0, stream>>>(query, Wq, bq, Qp);
        gemm_bt<0, float, half_t><<<gg, 256, 0, stream>>>(key,   Wk, bk, Kp);
        gemm_bt<2, float, half_t><<<gg, 256, 0, stream>>>(value, Wv, bv, VpT);
        attn_kernel<<<ga, 256, 0, stream>>>(Qp, Kp, VpT, Ob);
        gemm_bt<1, half_t, float><<<gg, 256, 0, stream>>>(Ob, Wo, bo, out);
    }
}